// Round 7
// baseline (105.249 us; speedup 1.0000x reference)
//
#include <hip/hip_runtime.h>
#include <hip/hip_bf16.h>
#include <hip/hip_fp16.h>
#include <math.h>

#define NN 2048

typedef _Float16 f16x8 __attribute__((ext_vector_type(8)));
typedef _Float16 h2    __attribute__((ext_vector_type(2)));
typedef float    f32x4 __attribute__((ext_vector_type(4)));
typedef float    f32x2 __attribute__((ext_vector_type(2)));

union H8 { h2 h[4]; f16x8 v; };

__device__ __forceinline__ h2 pkrtz(float a, float b){
  return __builtin_bit_cast(h2, __builtin_amdgcn_cvt_pkrtz(a, b));
}
__device__ __forceinline__ h2 hfma(h2 a, h2 b, h2 c){
  return __builtin_elementwise_fma(a, b, c);
}
__device__ __forceinline__ h2 hmax0(h2 a){
  h2 z = {(_Float16)0.f, (_Float16)0.f};
  return __builtin_elementwise_max(a, z);
}
__device__ __forceinline__ f32x2 pfma(f32x2 a, f32x2 b, f32x2 c){
  return __builtin_elementwise_fma(a, b, c);
}
__device__ __forceinline__ f32x2 pmax0(f32x2 a){
  f32x2 z = {0.f, 0.f};
  return __builtin_elementwise_max(a, z);
}

// ---------------- encode + qkv(iter1) + f16 weight prep ----------------
__global__ void k_encqkv(const float* __restrict__ x, const float* __restrict__ comms,
    const float* __restrict__ Wenc, const float* __restrict__ benc,
    const float* __restrict__ Wq, const float* __restrict__ bq,
    const float* __restrict__ Wk, const float* __restrict__ bk,
    const float* __restrict__ Wv, const float* __restrict__ bv,
    const float* __restrict__ W1, const float* __restrict__ b1,
    const float* __restrict__ W2,
    float* __restrict__ h, _Float16* __restrict__ qh, _Float16* __restrict__ kh,
    _Float16* __restrict__ vpk,
    _Float16* __restrict__ W1h, _Float16* __restrict__ b1h, _Float16* __restrict__ W2t)
{
  int t = threadIdx.x, b = blockIdx.x;
  if (b == 0){
    // one-time f16 weight prep (rewritten every launch: deterministic)
    if (t < 96) W1h[t] = (_Float16)W1[t];
    if (t < 32) b1h[t] = (_Float16)b1[t];
    #pragma unroll
    for (int idx = t; idx < 1024; idx += 256){
      int c2 = idx >> 5, c1 = idx & 31;
      W2t[idx] = (_Float16)W2[c1*32 + c2];   // W2t[c2][c1] = W2[c1][c2]
    }
  }
  int r = t >> 5, c = t & 31;
  int row = b*8 + r;
  float acc = benc[c];
  #pragma unroll
  for (int d=0; d<8; ++d) acc = fmaf(x[row*8+d],     Wenc[d*32+c],     acc);
  #pragma unroll
  for (int d=0; d<8; ++d) acc = fmaf(comms[row*8+d], Wenc[(8+d)*32+c], acc);
  __shared__ float hs[8][32];
  hs[r][c] = acc;
  h[row*32+c] = acc;
  __syncthreads();
  float aq=bq[c], ak=bk[c], av=bv[c];
  #pragma unroll 8
  for (int d=0; d<32; ++d){
    float hv = hs[r][d];
    aq = fmaf(hv, Wq[d*32+c], aq);
    ak = fmaf(hv, Wk[d*32+c], ak);
    av = fmaf(hv, Wv[d*32+c], av);
  }
  qh[row*32+c] = (_Float16)aq;
  kh[row*32+c] = (_Float16)ak;
  // v in PV-fragment layout: vpk[(j>>3)*256 + c*8 + (j&7)]
  vpk[b*256 + c*8 + r] = (_Float16)av;
}

// ---------------- pairwise-MLP logits: one 16x16 (i,j) tile per wave ----------------
// m-body is pure VALU+MFMA: dots pre-broadcast+splatted up front; packed f32x2 epilogue.
__launch_bounds__(256)
__global__ void k_logits(const _Float16* __restrict__ qh, const _Float16* __restrict__ kh,
    const float* __restrict__ adj, const float* __restrict__ dense,
    const _Float16* __restrict__ W1h, const _Float16* __restrict__ b1h,
    const _Float16* __restrict__ W2t,
    const float* __restrict__ b2, const float* __restrict__ W3,
    const float* __restrict__ b3,
    float* __restrict__ logits)
{
  int t = threadIdx.x;
  int wave = t >> 6;
  int l = t & 63;
  int lj = l & 15, g = l >> 4;
  int j0 = blockIdx.x * 64 + wave * 16;
  int i0 = blockIdx.y * 16;
  int c1b = 8*g;

  // dots = kk @ q^T on this 16x16 tile (A = k-rows i, B[k][j] = q[j][k])
  f16x8 af = *(const f16x8*)(kh + (i0+lj)*32 + c1b);
  f16x8 bq = *(const f16x8*)(qh + (j0+lj)*32 + c1b);
  f32x4 dacc = {0.f,0.f,0.f,0.f};
  dacc = __builtin_amdgcn_mfma_f32_16x16x32_f16(af, bq, dacc, 0, 0, 0);
  // dacc[r] = dots[i0+4g+r][j0+lj]

  // batched broadcast: pre-splatted f16 dots for all 16 m (no ds ops in m-body)
  h2 dsh[16];
  #pragma unroll
  for (int m=0;m<16;++m){
    float dv = __shfl(dacc[m & 3], ((m >> 2) << 4) + lj, 64);
    dsh[m] = pkrtz(dv, dv);
  }

  // per-lane W1/b1 as f16 channel-pairs (c1 = 8g..8g+7)
  h2 w10[4], w11[4], w12[4], b1v[4];
  #pragma unroll
  for (int p=0;p<4;++p){
    w10[p] = ((const h2*)(W1h      + c1b))[p];
    w11[p] = ((const h2*)(W1h + 32 + c1b))[p];
    w12[p] = ((const h2*)(W1h + 64 + c1b))[p];
    b1v[p] = ((const h2*)(b1h      + c1b))[p];
  }
  // A-frags for swapped W2 MFMA (A = W2^T): contiguous from pre-transposed W2t
  f16x8 w2f0 = *(const f16x8*)(W2t + lj*32 + c1b);
  f16x8 w2f1 = *(const f16x8*)(W2t + (16+lj)*32 + c1b);
  // b2 as MFMA C-in (rows c2 = 4g+r / 16+4g+r)
  f32x4 b2lo = *(const f32x4*)(b2 + 4*g);
  f32x4 b2hi = *(const f32x4*)(b2 + 16 + 4*g);
  // W3 as f32x2 pairs matching (a0[0..3], a1[0..3])
  f32x2 w3p0 = *(const f32x2*)(W3 + 4*g);
  f32x2 w3p1 = *(const f32x2*)(W3 + 4*g + 2);
  f32x2 w3p2 = *(const f32x2*)(W3 + 16 + 4*g);
  f32x2 w3p3 = *(const f32x2*)(W3 + 16 + 4*g + 2);
  float b3v = b3[0];

  // f32 preload of adj/dense (compile-time indexed; loads hoisted early)
  float adjv[16], denv[16];
  #pragma unroll
  for (int m=0;m<16;++m){
    adjv[m] = adj  [(i0+m)*NN + j0 + lj];
    denv[m] = dense[(i0+m)*NN + j0 + lj];
  }

  #pragma unroll
  for (int m=0;m<16;++m){
    h2 ah = pkrtz(adjv[m], adjv[m]);
    h2 eh = pkrtz(denv[m], denv[m]);
    // f1 = relu(feats @ W1 + b1): 4 f16 pairs; result IS the MFMA B-frag
    H8 fr;
    #pragma unroll
    for (int p=0;p<4;++p)
      fr.h[p] = hmax0(hfma(dsh[m], w10[p], hfma(ah, w11[p], hfma(eh, w12[p], b1v[p]))));
    // f2 + b2 via MFMA C-in: D[c2][pair], lane holds pair lj, c2 = 4g+r / 16+4g+r
    f32x4 a0 = __builtin_amdgcn_mfma_f32_16x16x32_f16(w2f0, fr.v, b2lo, 0,0,0);
    f32x4 a1 = __builtin_amdgcn_mfma_f32_16x16x32_f16(w2f1, fr.v, b2hi, 0,0,0);
    // relu + W3 dot: packed f32x2, 2 independent chains
    f32x2 q0 = pmax0((f32x2){a0[0], a0[1]});
    f32x2 q1 = pmax0((f32x2){a0[2], a0[3]});
    f32x2 q2 = pmax0((f32x2){a1[0], a1[1]});
    f32x2 q3 = pmax0((f32x2){a1[2], a1[3]});
    f32x2 sA = pfma(q1, w3p1, q0 * w3p0);
    f32x2 sB = pfma(q3, w3p3, q2 * w3p2);
    f32x2 s  = sA + sB;
    float tl = s[0] + s[1];
    tl += __shfl_xor(tl, 16, 64);
    tl += __shfl_xor(tl, 32, 64);
    tl += b3v;
    if (g == 0) logits[(i0+m)*NN + j0 + lj] = tl;
  }
}

// ---------------- softmax + focus@v + residual (+ fused qkv-next or decode) ----------------
template<int LAST>
__launch_bounds__(256)
__global__ void k_pv(const float* __restrict__ logits,
    const _Float16* __restrict__ vpk, const float* __restrict__ h_in,
    float* __restrict__ h_out,
    const float* __restrict__ Wq, const float* __restrict__ bq,
    const float* __restrict__ Wk, const float* __restrict__ bk,
    const float* __restrict__ Wv, const float* __restrict__ bv,
    _Float16* __restrict__ qn, _Float16* __restrict__ kn, _Float16* __restrict__ vpkn,
    const float* __restrict__ Wdec, const float* __restrict__ bdec,
    const float* __restrict__ mask, float* __restrict__ out)
{
  int t = threadIdx.x;
  int w = t >> 6;
  int l = t & 63;
  int li = l & 15, g = l >> 4;
  int i0 = blockIdx.x * 16;
  int jw = w * 512;
  const float* lrow = logits + (i0+li)*NN + jw + 8*g;

  // pre-pass: exact row max
  f32x4 mx4 = {-INFINITY,-INFINITY,-INFINITY,-INFINITY};
  for (int s=0; s<16; ++s){
    f32x4 p0 = *(const f32x4*)(lrow + s*32);
    f32x4 p1 = *(const f32x4*)(lrow + s*32 + 4);
    #pragma unroll
    for (int e=0;e<4;++e){ mx4[e] = fmaxf(mx4[e], p0[e]); mx4[e] = fmaxf(mx4[e], p1[e]); }
  }
  float mxl = fmaxf(fmaxf(mx4[0],mx4[1]), fmaxf(mx4[2],mx4[3]));
  mxl = fmaxf(mxl, __shfl_xor(mxl, 16, 64));
  mxl = fmaxf(mxl, __shfl_xor(mxl, 32, 64));
  __shared__ float Ms[4][16];
  if (l < 16) Ms[w][l] = mxl;
  __syncthreads();
  float Mrow = fmaxf(fmaxf(Ms[0][li],Ms[1][li]), fmaxf(Ms[2][li],Ms[3][li]));

  f32x4 acc0 = {0.f,0.f,0.f,0.f}, acc1 = {0.f,0.f,0.f,0.f};
  float Lp = 0.f;
  for (int s=0; s<16; ++s){
    int jb = jw + s*32 + 8*g;          // multiple of 8
    f32x4 p0 = *(const f32x4*)(lrow + s*32);
    f32x4 p1 = *(const f32x4*)(lrow + s*32 + 4);
    float ex[8];
    #pragma unroll
    for (int e=0;e<4;++e){ ex[e] = __expf(p0[e] - Mrow); ex[4+e] = __expf(p1[e] - Mrow); }
    H8 pfr;
    #pragma unroll
    for (int p=0;p<4;++p) pfr.h[p] = pkrtz(ex[2*p], ex[2*p+1]);
    Lp += ((ex[0]+ex[1])+(ex[2]+ex[3])) + ((ex[4]+ex[5])+(ex[6]+ex[7]));
    int base = (jb >> 3) * 256;
    f16x8 vf0 = *(const f16x8*)(vpk + base + li*8);
    f16x8 vf1 = *(const f16x8*)(vpk + base + (16+li)*8);
    acc0 = __builtin_amdgcn_mfma_f32_16x16x32_f16(pfr.v, vf0, acc0, 0,0,0);
    acc1 = __builtin_amdgcn_mfma_f32_16x16x32_f16(pfr.v, vf1, acc1, 0,0,0);
  }
  Lp += __shfl_xor(Lp, 16, 64);
  Lp += __shfl_xor(Lp, 32, 64);
  __shared__ float accs[4][16][32];
  __shared__ float Ls[4][16];
  __shared__ float hsn[16][32];
  #pragma unroll
  for (int r=0;r<4;++r){
    accs[w][4*g+r][li]    = acc0[r];
    accs[w][4*g+r][16+li] = acc1[r];
  }
  if (l < 16) Ls[w][l] = Lp;
  __syncthreads();
  for (int o = t; o < 512; o += 256){
    int i = o >> 5, c = o & 31;
    float s4 = accs[0][i][c] + accs[1][i][c] + accs[2][i][c] + accs[3][i][c];
    float L4 = Ls[0][i] + Ls[1][i] + Ls[2][i] + Ls[3][i];
    float hnew = h_in[(i0+i)*32 + c] + s4 / L4;
    hsn[i][c] = hnew;
    if (!LAST) h_out[(i0+i)*32+c] = hnew;
  }
  __syncthreads();
  if (!LAST){
    for (int o = t; o < 512; o += 256){
      int i = o >> 5, c = o & 31;
      float aq = bq[c], ak = bk[c], av = bv[c];
      #pragma unroll 8
      for (int d=0; d<32; ++d){
        float hv = hsn[i][d];
        aq = fmaf(hv, Wq[d*32+c], aq);
        ak = fmaf(hv, Wk[d*32+c], ak);
        av = fmaf(hv, Wv[d*32+c], av);
      }
      int row = i0 + i;
      qn[row*32+c] = (_Float16)aq;
      kn[row*32+c] = (_Float16)ak;
      vpkn[(row>>3)*256 + c*8 + (row&7)] = (_Float16)av;
    }
  } else {
    __shared__ float red[16][16];
    int ii = t >> 4, cs = t & 15;
    float part = hsn[ii][2*cs]*Wdec[2*cs] + hsn[ii][2*cs+1]*Wdec[2*cs+1];
    red[ii][cs] = part;
    __syncthreads();
    if (t < 16){
      float sacc = 0.f;
      #pragma unroll
      for (int e=0;e<16;++e) sacc += red[t][e];
      float o = sacc + bdec[0];
      float mk = mask[i0+t];
      out[i0+t] = o + (mk == 0.f ? -INFINITY : 0.f);
    }
  }
}

extern "C" void kernel_launch(void* const* d_in, const int* in_sizes, int n_in,
                              void* d_out, int out_size, void* d_ws, size_t ws_size,
                              hipStream_t stream)
{
  const float* x     = (const float*)d_in[0];
  const float* comms = (const float*)d_in[1];
  const float* adj   = (const float*)d_in[2];
  const float* dense = (const float*)d_in[3];
  const float* mask  = (const float*)d_in[4];
  const float* Wenc  = (const float*)d_in[5];
  const float* benc  = (const float*)d_in[6];
  const float* Wq    = (const float*)d_in[7];
  const float* bq    = (const float*)d_in[8];
  const float* Wk    = (const float*)d_in[9];
  const float* bk    = (const float*)d_in[10];
  const float* Wv    = (const float*)d_in[11];
  const float* bv    = (const float*)d_in[12];
  const float* W1    = (const float*)d_in[13];
  const float* b1    = (const float*)d_in[14];
  const float* W2    = (const float*)d_in[15];
  const float* b2    = (const float*)d_in[16];
  const float* W3    = (const float*)d_in[17];
  const float* b3    = (const float*)d_in[18];
  const float* Wdec  = (const float*)d_in[19];
  const float* bdec  = (const float*)d_in[20];
  float* out = (float*)d_out;

  float* logits = (float*)d_ws;
  float* h1 = logits + (size_t)NN*NN;
  float* h2 = h1 + NN*32;
  _Float16* qh1  = (_Float16*)(h2 + NN*32);
  _Float16* kh1  = qh1 + (size_t)NN*32;
  _Float16* qh2  = kh1 + (size_t)NN*32;
  _Float16* kh2  = qh2 + (size_t)NN*32;
  _Float16* vpk1 = kh2 + (size_t)NN*32;
  _Float16* vpk2 = vpk1 + (size_t)NN*32;
  _Float16* W1h  = vpk2 + (size_t)NN*32;  // 96
  _Float16* b1h  = W1h + 96;              // 32
  _Float16* W2t  = b1h + 32;              // 1024

  k_encqkv<<<256, 256, 0, stream>>>(x, comms, Wenc, benc, Wq,bq,Wk,bk,Wv,bv,
                                    W1, b1, W2,
                                    h1, qh1, kh1, vpk1, W1h, b1h, W2t);
  dim3 gl(32, 128);
  k_logits<<<gl, 256, 0, stream>>>(qh1, kh1, adj, dense, W1h, b1h, W2t,
                                   b2, W3, b3, logits);
  k_pv<0><<<128, 256, 0, stream>>>(logits, vpk1, h1, h2,
                                   Wq,bq,Wk,bk,Wv,bv, qh2,kh2,vpk2,
                                   nullptr, nullptr, nullptr, nullptr);
  k_logits<<<gl, 256, 0, stream>>>(qh2, kh2, adj, dense, W1h, b1h, W2t,
                                   b2, W3, b3, logits);
  k_pv<1><<<128, 256, 0, stream>>>(logits, vpk2, h2, nullptr,
                                   nullptr,nullptr,nullptr,nullptr,nullptr,nullptr,
                                   nullptr,nullptr,nullptr,
                                   Wdec, bdec, mask, out);
}

// Round 8
// 102.973 us; speedup vs baseline: 1.0221x; 1.0221x over previous
//
#include <hip/hip_runtime.h>
#include <hip/hip_bf16.h>
#include <hip/hip_fp16.h>
#include <math.h>

#define NN 2048

typedef _Float16 f16x8 __attribute__((ext_vector_type(8)));
typedef _Float16 h2    __attribute__((ext_vector_type(2)));
typedef float    f32x4 __attribute__((ext_vector_type(4)));
typedef float    f32x2 __attribute__((ext_vector_type(2)));

union H8 { h2 h[4]; f16x8 v; };

__device__ __forceinline__ h2 pkrtz(float a, float b){
  return __builtin_bit_cast(h2, __builtin_amdgcn_cvt_pkrtz(a, b));
}
__device__ __forceinline__ h2 hfma(h2 a, h2 b, h2 c){
  return __builtin_elementwise_fma(a, b, c);
}
__device__ __forceinline__ h2 hmax0(h2 a){
  h2 z = {(_Float16)0.f, (_Float16)0.f};
  return __builtin_elementwise_max(a, z);
}
__device__ __forceinline__ f32x2 pfma(f32x2 a, f32x2 b, f32x2 c){
  return __builtin_elementwise_fma(a, b, c);
}
__device__ __forceinline__ f32x2 pmax0(f32x2 a){
  f32x2 z = {0.f, 0.f};
  return __builtin_elementwise_max(a, z);
}

// ---- gfx950 VALU cross-lane swaps (no LDS pipe). Fallback: __shfl_xor. ----
#if __has_builtin(__builtin_amdgcn_permlane16_swap) && __has_builtin(__builtin_amdgcn_permlane32_swap)
#define HAVE_PERMLANE 1
__device__ __forceinline__ void pl16(float &x, float &y){
  auto r = __builtin_amdgcn_permlane16_swap(__builtin_bit_cast(unsigned, x),
                                            __builtin_bit_cast(unsigned, y), false, false);
  x = __builtin_bit_cast(float, (unsigned)r[0]);
  y = __builtin_bit_cast(float, (unsigned)r[1]);
}
__device__ __forceinline__ void pl32(float &x, float &y){
  auto r = __builtin_amdgcn_permlane32_swap(__builtin_bit_cast(unsigned, x),
                                            __builtin_bit_cast(unsigned, y), false, false);
  x = __builtin_bit_cast(float, (unsigned)r[0]);
  y = __builtin_bit_cast(float, (unsigned)r[1]);
}
__device__ __forceinline__ float redsum4g(float v){   // sum over lane^16 and lane^32
  float a = v, b = v; pl16(a, b); float s = a + b;
  float c = s, d = s; pl32(c, d); return c + d;
}
__device__ __forceinline__ float redmax4g(float v){
  float a = v, b = v; pl16(a, b); float s = fmaxf(a, b);
  float c = s, d = s; pl32(c, d); return fmaxf(c, d);
}
#else
#define HAVE_PERMLANE 0
__device__ __forceinline__ float redsum4g(float v){
  v += __shfl_xor(v, 16, 64); v += __shfl_xor(v, 32, 64); return v;
}
__device__ __forceinline__ float redmax4g(float v){
  v = fmaxf(v, __shfl_xor(v, 16, 64)); v = fmaxf(v, __shfl_xor(v, 32, 64)); return v;
}
#endif

// ---------------- encode + qkv(iter1) + f16 weight prep ----------------
__global__ void k_encqkv(const float* __restrict__ x, const float* __restrict__ comms,
    const float* __restrict__ Wenc, const float* __restrict__ benc,
    const float* __restrict__ Wq, const float* __restrict__ bq,
    const float* __restrict__ Wk, const float* __restrict__ bk,
    const float* __restrict__ Wv, const float* __restrict__ bv,
    const float* __restrict__ W1, const float* __restrict__ b1,
    const float* __restrict__ W2,
    float* __restrict__ h, _Float16* __restrict__ qh, _Float16* __restrict__ kh,
    _Float16* __restrict__ vpk,
    _Float16* __restrict__ W1h, _Float16* __restrict__ b1h, _Float16* __restrict__ W2t)
{
  int t = threadIdx.x, b = blockIdx.x;
  if (b == 0){
    if (t < 96) W1h[t] = (_Float16)W1[t];
    if (t < 32) b1h[t] = (_Float16)b1[t];
    #pragma unroll
    for (int idx = t; idx < 1024; idx += 256){
      int c2 = idx >> 5, c1 = idx & 31;
      W2t[idx] = (_Float16)W2[c1*32 + c2];   // W2t[c2][c1] = W2[c1][c2]
    }
  }
  int r = t >> 5, c = t & 31;
  int row = b*8 + r;
  float acc = benc[c];
  #pragma unroll
  for (int d=0; d<8; ++d) acc = fmaf(x[row*8+d],     Wenc[d*32+c],     acc);
  #pragma unroll
  for (int d=0; d<8; ++d) acc = fmaf(comms[row*8+d], Wenc[(8+d)*32+c], acc);
  __shared__ float hs[8][32];
  hs[r][c] = acc;
  h[row*32+c] = acc;
  __syncthreads();
  float aq=bq[c], ak=bk[c], av=bv[c];
  #pragma unroll 8
  for (int d=0; d<32; ++d){
    float hv = hs[r][d];
    aq = fmaf(hv, Wq[d*32+c], aq);
    ak = fmaf(hv, Wk[d*32+c], ak);
    av = fmaf(hv, Wv[d*32+c], av);
  }
  qh[row*32+c] = (_Float16)aq;
  kh[row*32+c] = (_Float16)ak;
  vpk[b*256 + c*8 + r] = (_Float16)av;   // vpk[(j>>3)*256 + c*8 + (j&7)]
}

// ---------------- pairwise-MLP logits: one 16x16 (i,j) tile per wave ----------------
// ZERO LDS-pipe ops: dots broadcast + logit reduce via permlane swaps (VALU).
__launch_bounds__(256)
__global__ void k_logits(const _Float16* __restrict__ qh, const _Float16* __restrict__ kh,
    const float* __restrict__ adj, const float* __restrict__ dense,
    const _Float16* __restrict__ W1h, const _Float16* __restrict__ b1h,
    const _Float16* __restrict__ W2t,
    const float* __restrict__ b2, const float* __restrict__ W3,
    const float* __restrict__ b3,
    float* __restrict__ logits)
{
  int t = threadIdx.x;
  int wave = t >> 6;
  int l = t & 63;
  int lj = l & 15, g = l >> 4;
  int j0 = blockIdx.x * 64 + wave * 16;
  int i0 = blockIdx.y * 16;
  int c1b = 8*g;

  // dots = kk @ q^T on this 16x16 tile (A = k-rows i, B[k][j] = q[j][k])
  f16x8 af = *(const f16x8*)(kh + (i0+lj)*32 + c1b);
  f16x8 bq = *(const f16x8*)(qh + (j0+lj)*32 + c1b);
  f32x4 dacc = {0.f,0.f,0.f,0.f};
  dacc = __builtin_amdgcn_mfma_f32_16x16x32_f16(af, bq, dacc, 0, 0, 0);
  // dacc[r] = dots[i0+4g+r][j0+lj]

  // broadcast all 16 rows to every lane via permlane butterfly (pure VALU)
  h2 dsh[16];
#if HAVE_PERMLANE
  #pragma unroll
  for (int r=0;r<4;++r){
    float a = dacc[r], b = dacc[r];
    pl16(a, b);                 // a=[R_r,R_r,R_{8+r},R_{8+r}], b=[R_{4+r},R_{4+r},R_{12+r},R_{12+r}]
    float a0 = a, a1 = a; pl32(a0, a1);   // a0=R_r (all), a1=R_{8+r} (all)
    float b0 = b, b1 = b; pl32(b0, b1);   // b0=R_{4+r},   b1=R_{12+r}
    dsh[r]      = pkrtz(a0, a0);
    dsh[4+r]    = pkrtz(b0, b0);
    dsh[8+r]    = pkrtz(a1, a1);
    dsh[12+r]   = pkrtz(b1, b1);
  }
#else
  #pragma unroll
  for (int m=0;m<16;++m){
    float dv = __shfl(dacc[m & 3], ((m >> 2) << 4) + lj, 64);
    dsh[m] = pkrtz(dv, dv);
  }
#endif

  // per-lane W1/b1 as f16 channel-pairs (c1 = 8g..8g+7)
  h2 w10[4], w11[4], w12[4], b1v[4];
  #pragma unroll
  for (int p=0;p<4;++p){
    w10[p] = ((const h2*)(W1h      + c1b))[p];
    w11[p] = ((const h2*)(W1h + 32 + c1b))[p];
    w12[p] = ((const h2*)(W1h + 64 + c1b))[p];
    b1v[p] = ((const h2*)(b1h      + c1b))[p];
  }
  // A-frags for swapped W2 MFMA (A = W2^T): contiguous from pre-transposed W2t
  f16x8 w2f0 = *(const f16x8*)(W2t + lj*32 + c1b);
  f16x8 w2f1 = *(const f16x8*)(W2t + (16+lj)*32 + c1b);
  // b2 as MFMA C-in (rows c2 = 4g+r / 16+4g+r)
  f32x4 b2lo = *(const f32x4*)(b2 + 4*g);
  f32x4 b2hi = *(const f32x4*)(b2 + 16 + 4*g);
  // W3 as f32x2 pairs matching (a0[0..3], a1[0..3])
  f32x2 w3p0 = *(const f32x2*)(W3 + 4*g);
  f32x2 w3p1 = *(const f32x2*)(W3 + 4*g + 2);
  f32x2 w3p2 = *(const f32x2*)(W3 + 16 + 4*g);
  f32x2 w3p3 = *(const f32x2*)(W3 + 16 + 4*g + 2);
  float b3v = b3[0];

  // f32 preload of adj/dense (compile-time indexed; loads hoisted early)
  float adjv[16], denv[16];
  #pragma unroll
  for (int m=0;m<16;++m){
    adjv[m] = adj  [(i0+m)*NN + j0 + lj];
    denv[m] = dense[(i0+m)*NN + j0 + lj];
  }

  #pragma unroll
  for (int m=0;m<16;++m){
    h2 ah = pkrtz(adjv[m], adjv[m]);
    h2 eh = pkrtz(denv[m], denv[m]);
    // f1 = relu(feats @ W1 + b1): 4 f16 pairs; result IS the MFMA B-frag
    H8 fr;
    #pragma unroll
    for (int p=0;p<4;++p)
      fr.h[p] = hmax0(hfma(dsh[m], w10[p], hfma(ah, w11[p], hfma(eh, w12[p], b1v[p]))));
    // f2 + b2 via MFMA C-in: D[c2][pair], lane holds pair lj, c2 = 4g+r / 16+4g+r
    f32x4 a0 = __builtin_amdgcn_mfma_f32_16x16x32_f16(w2f0, fr.v, b2lo, 0,0,0);
    f32x4 a1 = __builtin_amdgcn_mfma_f32_16x16x32_f16(w2f1, fr.v, b2hi, 0,0,0);
    // relu + W3 dot: packed f32x2, 2 independent chains
    f32x2 q0 = pmax0((f32x2){a0[0], a0[1]});
    f32x2 q1 = pmax0((f32x2){a0[2], a0[3]});
    f32x2 q2 = pmax0((f32x2){a1[0], a1[1]});
    f32x2 q3 = pmax0((f32x2){a1[2], a1[3]});
    f32x2 sA = pfma(q1, w3p1, q0 * w3p0);
    f32x2 sB = pfma(q3, w3p3, q2 * w3p2);
    f32x2 s  = sA + sB;
    // sum the 4 k-groups: pure-VALU permlane reduction
    float tl = redsum4g(s[0] + s[1]) + b3v;
    if (g == 0) logits[(i0+m)*NN + j0 + lj] = tl;
  }
}

// ---------------- softmax + focus@v + residual (+ fused qkv-next or decode) ----------------
template<int LAST>
__launch_bounds__(256)
__global__ void k_pv(const float* __restrict__ logits,
    const _Float16* __restrict__ vpk, const float* __restrict__ h_in,
    float* __restrict__ h_out,
    const float* __restrict__ Wq, const float* __restrict__ bq,
    const float* __restrict__ Wk, const float* __restrict__ bk,
    const float* __restrict__ Wv, const float* __restrict__ bv,
    _Float16* __restrict__ qn, _Float16* __restrict__ kn, _Float16* __restrict__ vpkn,
    const float* __restrict__ Wdec, const float* __restrict__ bdec,
    const float* __restrict__ mask, float* __restrict__ out)
{
  int t = threadIdx.x;
  int w = t >> 6;
  int l = t & 63;
  int li = l & 15, g = l >> 4;
  int i0 = blockIdx.x * 16;
  int jw = w * 512;
  const float* lrow = logits + (i0+li)*NN + jw + 8*g;

  // pre-pass: exact row max
  f32x4 mx4 = {-INFINITY,-INFINITY,-INFINITY,-INFINITY};
  for (int s=0; s<16; ++s){
    f32x4 p0 = *(const f32x4*)(lrow + s*32);
    f32x4 p1 = *(const f32x4*)(lrow + s*32 + 4);
    #pragma unroll
    for (int e=0;e<4;++e){ mx4[e] = fmaxf(mx4[e], p0[e]); mx4[e] = fmaxf(mx4[e], p1[e]); }
  }
  float mxl = redmax4g(fmaxf(fmaxf(mx4[0],mx4[1]), fmaxf(mx4[2],mx4[3])));
  __shared__ float Ms[4][16];
  if (l < 16) Ms[w][l] = mxl;
  __syncthreads();
  float Mrow = fmaxf(fmaxf(Ms[0][li],Ms[1][li]), fmaxf(Ms[2][li],Ms[3][li]));

  f32x4 acc0 = {0.f,0.f,0.f,0.f}, acc1 = {0.f,0.f,0.f,0.f};
  float Lp = 0.f;
  for (int s=0; s<16; ++s){
    int jb = jw + s*32 + 8*g;          // multiple of 8
    f32x4 p0 = *(const f32x4*)(lrow + s*32);
    f32x4 p1 = *(const f32x4*)(lrow + s*32 + 4);
    float ex[8];
    #pragma unroll
    for (int e=0;e<4;++e){ ex[e] = __expf(p0[e] - Mrow); ex[4+e] = __expf(p1[e] - Mrow); }
    H8 pfr;
    #pragma unroll
    for (int p=0;p<4;++p) pfr.h[p] = pkrtz(ex[2*p], ex[2*p+1]);
    Lp += ((ex[0]+ex[1])+(ex[2]+ex[3])) + ((ex[4]+ex[5])+(ex[6]+ex[7]));
    int base = (jb >> 3) * 256;
    f16x8 vf0 = *(const f16x8*)(vpk + base + li*8);
    f16x8 vf1 = *(const f16x8*)(vpk + base + (16+li)*8);
    acc0 = __builtin_amdgcn_mfma_f32_16x16x32_f16(pfr.v, vf0, acc0, 0,0,0);
    acc1 = __builtin_amdgcn_mfma_f32_16x16x32_f16(pfr.v, vf1, acc1, 0,0,0);
  }
  Lp = redsum4g(Lp);
  __shared__ float accs[4][16][32];
  __shared__ float Ls[4][16];
  __shared__ float hsn[16][32];
  #pragma unroll
  for (int r=0;r<4;++r){
    accs[w][4*g+r][li]    = acc0[r];
    accs[w][4*g+r][16+li] = acc1[r];
  }
  if (l < 16) Ls[w][l] = Lp;
  __syncthreads();
  for (int o = t; o < 512; o += 256){
    int i = o >> 5, c = o & 31;
    float s4 = accs[0][i][c] + accs[1][i][c] + accs[2][i][c] + accs[3][i][c];
    float L4 = Ls[0][i] + Ls[1][i] + Ls[2][i] + Ls[3][i];
    float hnew = h_in[(i0+i)*32 + c] + s4 / L4;
    hsn[i][c] = hnew;
    if (!LAST) h_out[(i0+i)*32+c] = hnew;
  }
  __syncthreads();
  if (!LAST){
    for (int o = t; o < 512; o += 256){
      int i = o >> 5, c = o & 31;
      float aq = bq[c], ak = bk[c], av = bv[c];
      #pragma unroll 8
      for (int d=0; d<32; ++d){
        float hv = hsn[i][d];
        aq = fmaf(hv, Wq[d*32+c], aq);
        ak = fmaf(hv, Wk[d*32+c], ak);
        av = fmaf(hv, Wv[d*32+c], av);
      }
      int row = i0 + i;
      qn[row*32+c] = (_Float16)aq;
      kn[row*32+c] = (_Float16)ak;
      vpkn[(row>>3)*256 + c*8 + (row&7)] = (_Float16)av;
    }
  } else {
    __shared__ float red[16][16];
    int ii = t >> 4, cs = t & 15;
    float part = hsn[ii][2*cs]*Wdec[2*cs] + hsn[ii][2*cs+1]*Wdec[2*cs+1];
    red[ii][cs] = part;
    __syncthreads();
    if (t < 16){
      float sacc = 0.f;
      #pragma unroll
      for (int e=0;e<16;++e) sacc += red[t][e];
      float o = sacc + bdec[0];
      float mk = mask[i0+t];
      out[i0+t] = o + (mk == 0.f ? -INFINITY : 0.f);
    }
  }
}

extern "C" void kernel_launch(void* const* d_in, const int* in_sizes, int n_in,
                              void* d_out, int out_size, void* d_ws, size_t ws_size,
                              hipStream_t stream)
{
  const float* x     = (const float*)d_in[0];
  const float* comms = (const float*)d_in[1];
  const float* adj   = (const float*)d_in[2];
  const float* dense = (const float*)d_in[3];
  const float* mask  = (const float*)d_in[4];
  const float* Wenc  = (const float*)d_in[5];
  const float* benc  = (const float*)d_in[6];
  const float* Wq    = (const float*)d_in[7];
  const float* bq    = (const float*)d_in[8];
  const float* Wk    = (const float*)d_in[9];
  const float* bk    = (const float*)d_in[10];
  const float* Wv    = (const float*)d_in[11];
  const float* bv    = (const float*)d_in[12];
  const float* W1    = (const float*)d_in[13];
  const float* b1    = (const float*)d_in[14];
  const float* W2    = (const float*)d_in[15];
  const float* b2    = (const float*)d_in[16];
  const float* W3    = (const float*)d_in[17];
  const float* b3    = (const float*)d_in[18];
  const float* Wdec  = (const float*)d_in[19];
  const float* bdec  = (const float*)d_in[20];
  float* out = (float*)d_out;

  float* logits = (float*)d_ws;
  float* h1 = logits + (size_t)NN*NN;
  float* h2 = h1 + NN*32;
  _Float16* qh1  = (_Float16*)(h2 + NN*32);
  _Float16* kh1  = qh1 + (size_t)NN*32;
  _Float16* qh2  = kh1 + (size_t)NN*32;
  _Float16* kh2  = qh2 + (size_t)NN*32;
  _Float16* vpk1 = kh2 + (size_t)NN*32;
  _Float16* vpk2 = vpk1 + (size_t)NN*32;
  _Float16* W1h  = vpk2 + (size_t)NN*32;  // 96
  _Float16* b1h  = W1h + 96;              // 32
  _Float16* W2t  = b1h + 32;              // 1024

  k_encqkv<<<256, 256, 0, stream>>>(x, comms, Wenc, benc, Wq,bq,Wk,bk,Wv,bv,
                                    W1, b1, W2,
                                    h1, qh1, kh1, vpk1, W1h, b1h, W2t);
  dim3 gl(32, 128);
  k_logits<<<gl, 256, 0, stream>>>(qh1, kh1, adj, dense, W1h, b1h, W2t,
                                   b2, W3, b3, logits);
  k_pv<0><<<128, 256, 0, stream>>>(logits, vpk1, h1, h2,
                                   Wq,bq,Wk,bk,Wv,bv, qh2,kh2,vpk2,
                                   nullptr, nullptr, nullptr, nullptr);
  k_logits<<<gl, 256, 0, stream>>>(qh2, kh2, adj, dense, W1h, b1h, W2t,
                                   b2, W3, b3, logits);
  k_pv<1><<<128, 256, 0, stream>>>(logits, vpk2, h2, nullptr,
                                   nullptr,nullptr,nullptr,nullptr,nullptr,nullptr,
                                   nullptr,nullptr,nullptr,
                                   Wdec, bdec, mask, out);
}

// Round 9
// 96.971 us; speedup vs baseline: 1.0854x; 1.0619x over previous
//
#include <hip/hip_runtime.h>
#include <hip/hip_bf16.h>
#include <hip/hip_fp16.h>
#include <math.h>

#define NN 2048

typedef _Float16 f16x8 __attribute__((ext_vector_type(8)));
typedef _Float16 h2    __attribute__((ext_vector_type(2)));
typedef float    f32x4 __attribute__((ext_vector_type(4)));
typedef float    f32x2 __attribute__((ext_vector_type(2)));

union H8 { h2 h[4]; f16x8 v; };

__device__ __forceinline__ h2 pkrtz(float a, float b){
  return __builtin_bit_cast(h2, __builtin_amdgcn_cvt_pkrtz(a, b));
}
__device__ __forceinline__ h2 hfma(h2 a, h2 b, h2 c){
  return __builtin_elementwise_fma(a, b, c);
}
__device__ __forceinline__ h2 hmax0(h2 a){
  h2 z = {(_Float16)0.f, (_Float16)0.f};
  return __builtin_elementwise_max(a, z);
}
__device__ __forceinline__ f32x2 pmax0f(f32x2 a){
  f32x2 z = {0.f, 0.f};
  return __builtin_elementwise_max(a, z);
}

// ---- gfx950 VALU cross-lane swaps (no LDS pipe). Fallback: __shfl_xor. ----
#if __has_builtin(__builtin_amdgcn_permlane16_swap) && __has_builtin(__builtin_amdgcn_permlane32_swap)
#define HAVE_PERMLANE 1
__device__ __forceinline__ void pl16(float &x, float &y){
  auto r = __builtin_amdgcn_permlane16_swap(__builtin_bit_cast(unsigned, x),
                                            __builtin_bit_cast(unsigned, y), false, false);
  x = __builtin_bit_cast(float, (unsigned)r[0]);
  y = __builtin_bit_cast(float, (unsigned)r[1]);
}
__device__ __forceinline__ void pl32(float &x, float &y){
  auto r = __builtin_amdgcn_permlane32_swap(__builtin_bit_cast(unsigned, x),
                                            __builtin_bit_cast(unsigned, y), false, false);
  x = __builtin_bit_cast(float, (unsigned)r[0]);
  y = __builtin_bit_cast(float, (unsigned)r[1]);
}
__device__ __forceinline__ float redsum4g(float v){
  float a = v, b = v; pl16(a, b); float s = a + b;
  float c = s, d = s; pl32(c, d); return c + d;
}
__device__ __forceinline__ float redmax4g(float v){
  float a = v, b = v; pl16(a, b); float s = fmaxf(a, b);
  float c = s, d = s; pl32(c, d); return fmaxf(c, d);
}
#else
#define HAVE_PERMLANE 0
__device__ __forceinline__ float redsum4g(float v){
  v += __shfl_xor(v, 16, 64); v += __shfl_xor(v, 32, 64); return v;
}
__device__ __forceinline__ float redmax4g(float v){
  v = fmaxf(v, __shfl_xor(v, 16, 64)); v = fmaxf(v, __shfl_xor(v, 32, 64)); return v;
}
#endif

// ---------------- encode + qkv(iter1) + f16 weight prep ----------------
__global__ void k_encqkv(const float* __restrict__ x, const float* __restrict__ comms,
    const float* __restrict__ Wenc, const float* __restrict__ benc,
    const float* __restrict__ Wq, const float* __restrict__ bq,
    const float* __restrict__ Wk, const float* __restrict__ bk,
    const float* __restrict__ Wv, const float* __restrict__ bv,
    const float* __restrict__ W1, const float* __restrict__ b1,
    const float* __restrict__ W2, const float* __restrict__ W3,
    float* __restrict__ h, _Float16* __restrict__ qh, _Float16* __restrict__ kh,
    _Float16* __restrict__ vpk,
    _Float16* __restrict__ W1h, _Float16* __restrict__ b1h,
    _Float16* __restrict__ W2t, _Float16* __restrict__ W3h)
{
  int t = threadIdx.x, b = blockIdx.x;
  if (b == 0){
    if (t < 96) W1h[t] = (_Float16)W1[t];
    if (t < 32) b1h[t] = (_Float16)b1[t];
    if (t < 32) W3h[t] = (_Float16)W3[t];
    // W2t rows 0-15: A0 rows m -> c2 = 8*(m>>2)+(m&3); rows 16-31: A1 -> +4.
    // Gives lane (g,lj) the c2=8g..8g+7 slice of f2 -> B-frag of the W3 MFMA.
    #pragma unroll
    for (int idx = t; idx < 1024; idx += 256){
      int r = idx >> 5, c1 = idx & 31;
      int rr = r & 15;
      int c2 = 8*(rr>>2) + (rr&3) + ((r >= 16) ? 4 : 0);
      W2t[idx] = (_Float16)W2[c1*32 + c2];
    }
  }
  int r = t >> 5, c = t & 31;
  int row = b*8 + r;
  float acc = benc[c];
  #pragma unroll
  for (int d=0; d<8; ++d) acc = fmaf(x[row*8+d],     Wenc[d*32+c],     acc);
  #pragma unroll
  for (int d=0; d<8; ++d) acc = fmaf(comms[row*8+d], Wenc[(8+d)*32+c], acc);
  __shared__ float hs[8][32];
  hs[r][c] = acc;
  h[row*32+c] = acc;
  __syncthreads();
  float aq=bq[c], ak=bk[c], av=bv[c];
  #pragma unroll 8
  for (int d=0; d<32; ++d){
    float hv = hs[r][d];
    aq = fmaf(hv, Wq[d*32+c], aq);
    ak = fmaf(hv, Wk[d*32+c], ak);
    av = fmaf(hv, Wv[d*32+c], av);
  }
  qh[row*32+c] = (_Float16)aq;
  kh[row*32+c] = (_Float16)ak;
  vpk[b*256 + c*8 + r] = (_Float16)av;   // vpk[(j>>3)*256 + c*8 + (j&7)]
}

// ---------------- pairwise-MLP logits: one 16x16 (i,j) tile per wave ----------------
// 3-MFMA pipeline per m: W2(x2, row-permuted) then W3 as a third MFMA.
// Epilogue per m: 4 pk_max + 4 cvt_pk + 1 MFMA; logit lands on g==0 lanes.
__launch_bounds__(256)
__global__ void k_logits(const _Float16* __restrict__ qh, const _Float16* __restrict__ kh,
    const float* __restrict__ adj, const float* __restrict__ dense,
    const _Float16* __restrict__ W1h, const _Float16* __restrict__ b1h,
    const _Float16* __restrict__ W2t, const _Float16* __restrict__ W3h,
    const float* __restrict__ b2, const float* __restrict__ b3,
    float* __restrict__ logits)
{
  int t = threadIdx.x;
  int wave = t >> 6;
  int l = t & 63;
  int lj = l & 15, g = l >> 4;
  int j0 = blockIdx.x * 64 + wave * 16;
  int i0 = blockIdx.y * 16;
  int c1b = 8*g;

  // dots = kk @ q^T on this 16x16 tile (A = k-rows i, B[k][j] = q[j][k])
  f16x8 af = *(const f16x8*)(kh + (i0+lj)*32 + c1b);
  f16x8 bq = *(const f16x8*)(qh + (j0+lj)*32 + c1b);
  f32x4 dacc = {0.f,0.f,0.f,0.f};
  dacc = __builtin_amdgcn_mfma_f32_16x16x32_f16(af, bq, dacc, 0, 0, 0);
  // dacc[r] = dots[i0+4g+r][j0+lj]

  // broadcast all 16 rows to every lane via permlane butterfly (pure VALU)
  h2 dsh[16];
#if HAVE_PERMLANE
  #pragma unroll
  for (int r=0;r<4;++r){
    float a = dacc[r], b = dacc[r];
    pl16(a, b);
    float a0 = a, a1 = a; pl32(a0, a1);
    float b0 = b, b1 = b; pl32(b0, b1);
    dsh[r]    = pkrtz(a0, a0);
    dsh[4+r]  = pkrtz(b0, b0);
    dsh[8+r]  = pkrtz(a1, a1);
    dsh[12+r] = pkrtz(b1, b1);
  }
#else
  #pragma unroll
  for (int m=0;m<16;++m){
    float dv = __shfl(dacc[m & 3], ((m >> 2) << 4) + lj, 64);
    dsh[m] = pkrtz(dv, dv);
  }
#endif

  // per-lane W1/b1 as f16 channel-pairs (c1 = 8g..8g+7)
  h2 w10[4], w11[4], w12[4], b1v[4];
  #pragma unroll
  for (int p=0;p<4;++p){
    w10[p] = ((const h2*)(W1h      + c1b))[p];
    w11[p] = ((const h2*)(W1h + 32 + c1b))[p];
    w12[p] = ((const h2*)(W1h + 64 + c1b))[p];
    b1v[p] = ((const h2*)(b1h      + c1b))[p];
  }
  // A-frags for W2 MFMAs (row-permuted W2^T)
  f16x8 w2f0 = *(const f16x8*)(W2t + lj*32 + c1b);
  f16x8 w2f1 = *(const f16x8*)(W2t + (16+lj)*32 + c1b);
  // b2 C-in: lane (g,lj) rows are c2 = 8g+r (MFMA0) / 8g+4+r (MFMA1) -> contiguous
  f32x4 b2lo = *(const f32x4*)(b2 + 8*g);
  f32x4 b2hi = *(const f32x4*)(b2 + 8*g + 4);
  // W3 MFMA A-frag: row 0 = W3, rows 1-15 = 0.  Lane (g,lj) holds A[lj][8g..8g+7].
  f16x8 w3f = {(_Float16)0.f,(_Float16)0.f,(_Float16)0.f,(_Float16)0.f,
               (_Float16)0.f,(_Float16)0.f,(_Float16)0.f,(_Float16)0.f};
  if (lj == 0) w3f = *(const f16x8*)(W3h + c1b);
  // b3 C-in on row 0 (lanes g==0, reg 0)
  f32x4 c3 = {0.f,0.f,0.f,0.f};
  if (g == 0) c3[0] = b3[0];

  // pre-splatted f16 adj/dense (hoisted; compile-time indexed)
  h2 adjh[16], denh[16];
  #pragma unroll
  for (int m=0;m<16;++m){
    float a_ = adj  [(i0+m)*NN + j0 + lj];
    float d_ = dense[(i0+m)*NN + j0 + lj];
    adjh[m] = pkrtz(a_, a_);
    denh[m] = pkrtz(d_, d_);
  }

  #pragma unroll
  for (int m=0;m<16;++m){
    // f1 = relu(feats @ W1 + b1): 4 f16 pairs; result IS the MFMA B-frag
    H8 fr;
    #pragma unroll
    for (int p=0;p<4;++p)
      fr.h[p] = hmax0(hfma(dsh[m], w10[p], hfma(adjh[m], w11[p], hfma(denh[m], w12[p], b1v[p]))));
    // f2 + b2 via MFMA C-in (row-permuted): a0[r]=f2[8g+r], a1[r]=f2[8g+4+r], col lj
    f32x4 a0 = __builtin_amdgcn_mfma_f32_16x16x32_f16(w2f0, fr.v, b2lo, 0,0,0);
    f32x4 a1 = __builtin_amdgcn_mfma_f32_16x16x32_f16(w2f1, fr.v, b2hi, 0,0,0);
    // relu + pack to f16: this lane's c2=8g..8g+7 slice -> B-frag of W3 MFMA
    f32x2 q01 = pmax0f((f32x2){a0[0], a0[1]});
    f32x2 q23 = pmax0f((f32x2){a0[2], a0[3]});
    f32x2 q45 = pmax0f((f32x2){a1[0], a1[1]});
    f32x2 q67 = pmax0f((f32x2){a1[2], a1[3]});
    H8 pr;
    pr.h[0] = pkrtz(q01[0], q01[1]);
    pr.h[1] = pkrtz(q23[0], q23[1]);
    pr.h[2] = pkrtz(q45[0], q45[1]);
    pr.h[3] = pkrtz(q67[0], q67[1]);
    // logit[m][lj] = W3 . relu(f2) + b3 via MFMA row 0
    f32x4 d3 = __builtin_amdgcn_mfma_f32_16x16x32_f16(w3f, pr.v, c3, 0,0,0);
    if (g == 0) logits[(i0+m)*NN + j0 + lj] = d3[0];
  }
}

// ---------------- softmax + focus@v + residual (+ fused qkv-next or decode) ----------------
template<int LAST>
__launch_bounds__(256)
__global__ void k_pv(const float* __restrict__ logits,
    const _Float16* __restrict__ vpk, const float* __restrict__ h_in,
    float* __restrict__ h_out,
    const float* __restrict__ Wq, const float* __restrict__ bq,
    const float* __restrict__ Wk, const float* __restrict__ bk,
    const float* __restrict__ Wv, const float* __restrict__ bv,
    _Float16* __restrict__ qn, _Float16* __restrict__ kn, _Float16* __restrict__ vpkn,
    const float* __restrict__ Wdec, const float* __restrict__ bdec,
    const float* __restrict__ mask, float* __restrict__ out)
{
  int t = threadIdx.x;
  int w = t >> 6;
  int l = t & 63;
  int li = l & 15, g = l >> 4;
  int i0 = blockIdx.x * 16;
  int jw = w * 512;
  const float* lrow = logits + (i0+li)*NN + jw + 8*g;

  // pre-pass: exact row max
  f32x4 mx4 = {-INFINITY,-INFINITY,-INFINITY,-INFINITY};
  for (int s=0; s<16; ++s){
    f32x4 p0 = *(const f32x4*)(lrow + s*32);
    f32x4 p1 = *(const f32x4*)(lrow + s*32 + 4);
    #pragma unroll
    for (int e=0;e<4;++e){ mx4[e] = fmaxf(mx4[e], p0[e]); mx4[e] = fmaxf(mx4[e], p1[e]); }
  }
  float mxl = redmax4g(fmaxf(fmaxf(mx4[0],mx4[1]), fmaxf(mx4[2],mx4[3])));
  __shared__ float Ms[4][16];
  if (l < 16) Ms[w][l] = mxl;
  __syncthreads();
  float Mrow = fmaxf(fmaxf(Ms[0][li],Ms[1][li]), fmaxf(Ms[2][li],Ms[3][li]));

  f32x4 acc0 = {0.f,0.f,0.f,0.f}, acc1 = {0.f,0.f,0.f,0.f};
  float Lp = 0.f;
  for (int s=0; s<16; ++s){
    int jb = jw + s*32 + 8*g;          // multiple of 8
    f32x4 p0 = *(const f32x4*)(lrow + s*32);
    f32x4 p1 = *(const f32x4*)(lrow + s*32 + 4);
    float ex[8];
    #pragma unroll
    for (int e=0;e<4;++e){ ex[e] = __expf(p0[e] - Mrow); ex[4+e] = __expf(p1[e] - Mrow); }
    H8 pfr;
    #pragma unroll
    for (int p=0;p<4;++p) pfr.h[p] = pkrtz(ex[2*p], ex[2*p+1]);
    Lp += ((ex[0]+ex[1])+(ex[2]+ex[3])) + ((ex[4]+ex[5])+(ex[6]+ex[7]));
    int base = (jb >> 3) * 256;
    f16x8 vf0 = *(const f16x8*)(vpk + base + li*8);
    f16x8 vf1 = *(const f16x8*)(vpk + base + (16+li)*8);
    acc0 = __builtin_amdgcn_mfma_f32_16x16x32_f16(pfr.v, vf0, acc0, 0,0,0);
    acc1 = __builtin_amdgcn_mfma_f32_16x16x32_f16(pfr.v, vf1, acc1, 0,0,0);
  }
  Lp = redsum4g(Lp);
  __shared__ float accs[4][16][32];
  __shared__ float Ls[4][16];
  __shared__ float hsn[16][32];
  #pragma unroll
  for (int r=0;r<4;++r){
    accs[w][4*g+r][li]    = acc0[r];
    accs[w][4*g+r][16+li] = acc1[r];
  }
  if (l < 16) Ls[w][l] = Lp;
  __syncthreads();
  for (int o = t; o < 512; o += 256){
    int i = o >> 5, c = o & 31;
    float s4 = accs[0][i][c] + accs[1][i][c] + accs[2][i][c] + accs[3][i][c];
    float L4 = Ls[0][i] + Ls[1][i] + Ls[2][i] + Ls[3][i];
    float hnew = h_in[(i0+i)*32 + c] + s4 / L4;
    hsn[i][c] = hnew;
    if (!LAST) h_out[(i0+i)*32+c] = hnew;
  }
  __syncthreads();
  if (!LAST){
    for (int o = t; o < 512; o += 256){
      int i = o >> 5, c = o & 31;
      float aq = bq[c], ak = bk[c], av = bv[c];
      #pragma unroll 8
      for (int d=0; d<32; ++d){
        float hv = hsn[i][d];
        aq = fmaf(hv, Wq[d*32+c], aq);
        ak = fmaf(hv, Wk[d*32+c], ak);
        av = fmaf(hv, Wv[d*32+c], av);
      }
      int row = i0 + i;
      qn[row*32+c] = (_Float16)aq;
      kn[row*32+c] = (_Float16)ak;
      vpkn[(row>>3)*256 + c*8 + (row&7)] = (_Float16)av;
    }
  } else {
    __shared__ float red[16][16];
    int ii = t >> 4, cs = t & 15;
    float part = hsn[ii][2*cs]*Wdec[2*cs] + hsn[ii][2*cs+1]*Wdec[2*cs+1];
    red[ii][cs] = part;
    __syncthreads();
    if (t < 16){
      float sacc = 0.f;
      #pragma unroll
      for (int e=0;e<16;++e) sacc += red[t][e];
      float o = sacc + bdec[0];
      float mk = mask[i0+t];
      out[i0+t] = o + (mk == 0.f ? -INFINITY : 0.f);
    }
  }
}

extern "C" void kernel_launch(void* const* d_in, const int* in_sizes, int n_in,
                              void* d_out, int out_size, void* d_ws, size_t ws_size,
                              hipStream_t stream)
{
  const float* x     = (const float*)d_in[0];
  const float* comms = (const float*)d_in[1];
  const float* adj   = (const float*)d_in[2];
  const float* dense = (const float*)d_in[3];
  const float* mask  = (const float*)d_in[4];
  const float* Wenc  = (const float*)d_in[5];
  const float* benc  = (const float*)d_in[6];
  const float* Wq    = (const float*)d_in[7];
  const float* bq    = (const float*)d_in[8];
  const float* Wk    = (const float*)d_in[9];
  const float* bk    = (const float*)d_in[10];
  const float* Wv    = (const float*)d_in[11];
  const float* bv    = (const float*)d_in[12];
  const float* W1    = (const float*)d_in[13];
  const float* b1    = (const float*)d_in[14];
  const float* W2    = (const float*)d_in[15];
  const float* b2    = (const float*)d_in[16];
  const float* W3    = (const float*)d_in[17];
  const float* b3    = (const float*)d_in[18];
  const float* Wdec  = (const float*)d_in[19];
  const float* bdec  = (const float*)d_in[20];
  float* out = (float*)d_out;

  float* logits = (float*)d_ws;
  float* h1 = logits + (size_t)NN*NN;
  float* h2 = h1 + NN*32;
  _Float16* qh1  = (_Float16*)(h2 + NN*32);
  _Float16* kh1  = qh1 + (size_t)NN*32;
  _Float16* qh2  = kh1 + (size_t)NN*32;
  _Float16* kh2  = qh2 + (size_t)NN*32;
  _Float16* vpk1 = kh2 + (size_t)NN*32;
  _Float16* vpk2 = vpk1 + (size_t)NN*32;
  _Float16* W1h  = vpk2 + (size_t)NN*32;  // 96
  _Float16* b1h  = W1h + 96;              // 32
  _Float16* W2t  = b1h + 32;              // 1024
  _Float16* W3h  = W2t + 1024;            // 32

  k_encqkv<<<256, 256, 0, stream>>>(x, comms, Wenc, benc, Wq,bq,Wk,bk,Wv,bv,
                                    W1, b1, W2, W3,
                                    h1, qh1, kh1, vpk1, W1h, b1h, W2t, W3h);
  dim3 gl(32, 128);
  k_logits<<<gl, 256, 0, stream>>>(qh1, kh1, adj, dense, W1h, b1h, W2t, W3h,
                                   b2, b3, logits);
  k_pv<0><<<128, 256, 0, stream>>>(logits, vpk1, h1, h2,
                                   Wq,bq,Wk,bk,Wv,bv, qh2,kh2,vpk2,
                                   nullptr, nullptr, nullptr, nullptr);
  k_logits<<<gl, 256, 0, stream>>>(qh2, kh2, adj, dense, W1h, b1h, W2t, W3h,
                                   b2, b3, logits);
  k_pv<1><<<128, 256, 0, stream>>>(logits, vpk2, h2, nullptr,
                                   nullptr,nullptr,nullptr,nullptr,nullptr,nullptr,
                                   nullptr,nullptr,nullptr,
                                   Wdec, bdec, mask, out);
}